// Round 14
// baseline (486.615 us; speedup 1.0000x reference)
//
#include <hip/hip_runtime.h>
#include <hip/hip_bf16.h>
#include <stdint.h>

#define TOTAL 4096
#define EMB 384
#define MD 32
#define NDOCS (TOTAL - 1 - MD)   // 4063
#define LN_EPS 1e-5f
#define NBLK 256
#define NTHR 512

typedef __hip_bfloat16 bf16;
typedef unsigned short ushort_t;
typedef __attribute__((ext_vector_type(8))) short short8;
typedef __attribute__((ext_vector_type(4))) float f32x4;
typedef __attribute__((ext_vector_type(2))) float f32x2;

__device__ __forceinline__ float ldf(const void* p, int i, int isbf) {
    return isbf ? __bfloat162float(((const bf16*)p)[i]) : ((const float*)p)[i];
}
__device__ __forceinline__ unsigned f2bf(float x) {
    return (__float_as_uint(x) + 0x8000u) >> 16;
}
__device__ __forceinline__ unsigned fenc(float f) {
    unsigned u = __float_as_uint(f);
    return (u >> 31) ? ~u : (u | 0x80000000u);
}
__device__ __forceinline__ float fdec(unsigned k) {
    return __uint_as_float((k & 0x80000000u) ? (k & 0x7FFFFFFFu) : ~k);
}

// Software grid barrier: monotonic per-stage counter. 256 blk x 512 thr @ <=256 VGPR
// (launch_bounds), 33KB LDS -> co-resident. BOUNDED spin (hang -> wrong answer, not
// container kill). Relaxed spin + one threadfence: avoids per-iteration buffer_inv.
__device__ __forceinline__ void gbar(unsigned* barr, int k) {
    __syncthreads();
    if (threadIdx.x == 0) {
        unsigned* c = barr + k * 32;
        __hip_atomic_fetch_add(c, 1u, __ATOMIC_ACQ_REL, __HIP_MEMORY_SCOPE_AGENT);
        int spins = 0;
        while (__hip_atomic_load(c, __ATOMIC_RELAXED, __HIP_MEMORY_SCOPE_AGENT) < NBLK &&
               spins < 50000) {
            __builtin_amdgcn_s_sleep(8);
            spins++;
        }
        __threadfence();   // acquire: pairs with other blocks' release fetch_add
    }
    __syncthreads();
}

#define NTOT (EMB * 256 + 2 * 65536 + 514 * 256)   // 360960 transpose elems

__global__ __launch_bounds__(NTHR, 2) void k_mega(
    const int* adj, const void* emb, const void* proj_w, const void* gat_W,
    const void* fusion_w, const void* proj_b, const void* ln_scale, const void* ln_bias,
    const void* gat_a, const void* fusion_b, const void* out_w, const void* out_bp,
    void* outv, unsigned* barr,
    unsigned long long* maskb, unsigned* dmaxu,
    float* projT, float* gatT, float* fwT,
    float* h, float* srcb, unsigned* d12g, ushort_t* whswz,
    float* hnp, float* lpart, float* scoresv, float* cosv, float* awv, float* qrow) {
    __shared__ __align__(16) char arena[33344];
    int t = threadIdx.x, b = blockIdx.x;
    int wv_ = t >> 6, lane = t & 63;
    const float LOG2E = 1.44269504f;

    // ---- per-block dtype detect ----
    int isbf;
    {
        int* red = (int*)arena;
        int cnt = 0;
        for (int k = t; k < 4096; k += NTHR) {
            uint16_t wd = ((const uint16_t*)emb)[2 * k];
            int e = (wd >> 7) & 0xFF;
            cnt += (e >= 100 && e <= 140);
        }
        for (int o = 32; o > 0; o >>= 1) cnt += __shfl_down(cnt, o);
        if (lane == 0) red[wv_] = cnt;
        __syncthreads();
        int tot = 0;
#pragma unroll
        for (int i = 0; i < 8; i++) tot += red[i];
        isbf = tot > 2048;
        __syncthreads();
    }

    // ---- S0: adj->bitmask (wave per 2 rows), dmax init, weight transpose ----
    {
        int row0 = b * 16 + wv_ * 2;
#pragma unroll
        for (int rr = 0; rr < 2; rr++) {
            int row = row0 + rr;
            for (int c0 = 0; c0 < 64; c0 += 8) {
                int a[8];
#pragma unroll
                for (int u = 0; u < 8; u++) a[u] = adj[(size_t)row * TOTAL + (c0 + u) * 64 + lane];
#pragma unroll
                for (int u = 0; u < 8; u++) {
                    unsigned long long m = __ballot(a[u] != 0);
                    if (lane == 0) maskb[row * 64 + c0 + u] = m;
                }
            }
        }
        if (b == 0) for (int idx = t; idx < 2048; idx += NTHR) dmaxu[idx] = 0x007FFFFFu;
        for (int idx = b * NTHR + t; idx < NTOT; idx += NBLK * NTHR) {
            if (idx < EMB * 256) {
                int d = idx >> 8, c = idx & 255;
                projT[idx] = ldf(proj_w, c * EMB + d, isbf);
            } else if (idx < EMB * 256 + 2 * 65536) {
                int r = idx - EMB * 256;
                int ll = r >> 16, rem = r & 65535;
                int d = rem >> 8, c = rem & 255;
                gatT[r] = ldf(gat_W, ll * 65536 + c * 256 + d, isbf);
            } else {
                int r = idx - (EMB * 256 + 2 * 65536);
                int j = r >> 8, c = r & 255;
                fwT[r] = ldf(fusion_w, c * 514 + j, isbf);
            }
        }
    }
    gbar(barr, 0);

    // ---- S1: h = relu(emb @ projT + b), 16 rows/block, 2 col-groups x 8 rows ----
    {
        float* xs = (float*)arena;                 // [16][EMB] 24576B
        int col = t & 255, g = t >> 8;
        int i0 = b * 16;
        for (int idx = t; idx < 16 * EMB; idx += NTHR) {
            int r = idx / EMB, d = idx - r * EMB;
            xs[r * EMB + d] = ldf(emb, (i0 + r) * EMB + d, isbf);
        }
        __syncthreads();
        float acc[8];
        float bias = ldf(proj_b, col, isbf);
#pragma unroll
        for (int r = 0; r < 8; r++) acc[r] = bias;
        for (int d0 = 0; d0 < EMB; d0 += 4) {
            float w0 = projT[d0 * 256 + col];
            float w1 = projT[(d0 + 1) * 256 + col];
            float w2 = projT[(d0 + 2) * 256 + col];
            float w3 = projT[(d0 + 3) * 256 + col];
#pragma unroll
            for (int r = 0; r < 8; r++) {
                float4 x = *(const float4*)&xs[(g * 8 + r) * EMB + d0];
                acc[r] = fmaf(x.x, w0, acc[r]); acc[r] = fmaf(x.y, w1, acc[r]);
                acc[r] = fmaf(x.z, w2, acc[r]); acc[r] = fmaf(x.w, w3, acc[r]);
            }
        }
#pragma unroll
        for (int r = 0; r < 8; r++)
            h[(size_t)(i0 + g * 8 + r) * 256 + col] = fmaxf(acc[r], 0.f);
    }
    gbar(barr, 1);

    // ---- S2: s += 0.8*cos(q,s)*q, wave per 2 docs ----
    {
        float4* h4 = (float4*)h;
        float4 q4 = h4[lane];
        float a = q4.x * q4.x + q4.y * q4.y + q4.z * q4.z + q4.w * q4.w;
        for (int o = 32; o > 0; o >>= 1) a += __shfl_xor(a, o);
        float qn = sqrtf(a) + 1e-8f;
#pragma unroll
        for (int v = 0; v < 2; v++) {
            int n = v * 2048 + b * 8 + wv_;
            if (n < NDOCS) {
                size_t ro = (size_t)(1 + MD + n) * 64;
                float4 s4 = h4[ro + lane];
                float bb = s4.x * s4.x + s4.y * s4.y + s4.z * s4.z + s4.w * s4.w;
                float cc = q4.x * s4.x + q4.y * s4.y + q4.z * s4.z + q4.w * s4.w;
                for (int o = 32; o > 0; o >>= 1) { bb += __shfl_xor(bb, o); cc += __shfl_xor(cc, o); }
                float k = 0.8f * (cc / (qn * (sqrtf(bb) + 1e-8f)));
                s4.x += k * q4.x; s4.y += k * q4.y; s4.z += k * q4.z; s4.w += k * q4.w;
                h4[ro + lane] = s4;
            }
        }
    }
    gbar(barr, 2);

    for (int layer = 0; layer < 2; layer++) {
        // ---- S3/S5: [prev-layer epilogue] + LN + Wh GEMM + src/dst, 16 rows/block ----
        {
            float* xs = (float*)arena;             // [16][256] 16KB
            float* redA = (float*)(arena + 16384); // [16][4]
            float* redB = (float*)(arena + 16640); // [16][4]
            unsigned* dml = dmaxu + layer * 1024;
            int col = t & 255, g = t >> 8, head = col >> 6, w4 = wv_ & 3;
            int i0 = b * 16;
            float scale = ldf(ln_scale, layer * 256 + col, isbf);
            float bias = ldf(ln_bias, layer * 256 + col, isbf);
            float hv[8];
            if (layer == 1) {
#pragma unroll
                for (int r = 0; r < 8; r++) {
                    int i = i0 + g * 8 + r;
                    float lsum = lpart[(size_t)head * 4096 + i] +
                                 lpart[(size_t)(4 + head) * 4096 + i];
                    float s = hnp[(size_t)i * 256 + col] +
                              hnp[(size_t)TOTAL * 256 + i * 256 + col];
                    float hn = 0.5f * fmaxf(s / lsum, 0.f) + 0.5f * h[(size_t)i * 256 + col];
                    hv[r] = hn;
                    h[(size_t)i * 256 + col] = hn;
                }
            } else {
#pragma unroll
                for (int r = 0; r < 8; r++) hv[r] = h[(size_t)(i0 + g * 8 + r) * 256 + col];
            }
#pragma unroll
            for (int r = 0; r < 8; r++) {
                float a = hv[r], bsq = hv[r] * hv[r];
                for (int o = 32; o > 0; o >>= 1) { a += __shfl_down(a, o); bsq += __shfl_down(bsq, o); }
                if (lane == 0) { redA[(g * 8 + r) * 4 + w4] = a; redB[(g * 8 + r) * 4 + w4] = bsq; }
            }
            __syncthreads();
#pragma unroll
            for (int r = 0; r < 8; r++) {
                int rr = g * 8 + r;
                float mu = (redA[rr * 4] + redA[rr * 4 + 1] + redA[rr * 4 + 2] + redA[rr * 4 + 3]) * (1.f / 256.f);
                float var = (redB[rr * 4] + redB[rr * 4 + 1] + redB[rr * 4 + 2] + redB[rr * 4 + 3]) * (1.f / 256.f) - mu * mu;
                xs[rr * 256 + col] = (hv[r] - mu) * rsqrtf(var + LN_EPS) * scale + bias;
            }
            __syncthreads();
            const float* gT = gatT + layer * 65536;
            float acc[8] = {0.f, 0.f, 0.f, 0.f, 0.f, 0.f, 0.f, 0.f};
            for (int d0 = 0; d0 < 256; d0 += 4) {
                float w0 = gT[d0 * 256 + col];
                float w1 = gT[(d0 + 1) * 256 + col];
                float w2 = gT[(d0 + 2) * 256 + col];
                float w3 = gT[(d0 + 3) * 256 + col];
#pragma unroll
                for (int r = 0; r < 8; r++) {
                    float4 x = *(const float4*)&xs[(g * 8 + r) * 256 + d0];
                    acc[r] = fmaf(x.x, w0, acc[r]); acc[r] = fmaf(x.y, w1, acc[r]);
                    acc[r] = fmaf(x.z, w2, acc[r]); acc[r] = fmaf(x.w, w3, acc[r]);
                }
            }
            float av1 = ldf(gat_a, layer * 512 + head * 128 + (col & 63), isbf);
            float av2 = ldf(gat_a, layer * 512 + head * 128 + 64 + (col & 63), isbf);
            float mmax = -__builtin_inff();
#pragma unroll
            for (int r = 0; r < 8; r++) {
                int i = i0 + g * 8 + r;
                int off = (i >> 6) * 16384 + head * 4096 + ((i >> 3) & 7) * 512 +
                          ((col >> 4) & 3) * 128 + (col & 15) * 8 + (i & 7);
                whswz[off] = (ushort_t)f2bf(acc[r]);
                float sv = acc[r] * av1, dv = acc[r] * av2;
                for (int o = 32; o > 0; o >>= 1) { sv += __shfl_down(sv, o); dv += __shfl_down(dv, o); }
                if (lane == 0) {
                    srcb[head * 4096 + i] = sv;
                    float D1 = exp2f(dv * LOG2E), D2 = exp2f(0.2f * dv * LOG2E);
                    d12g[head * 4096 + i] = (f2bf(D2) << 16) | f2bf(D1);
                    mmax = fmaxf(mmax, dv);
                }
            }
            if (lane == 0) atomicMax(&dml[(b & 63) * 16 + head], fenc(mmax));
        }
        gbar(barr, 3 + layer * 2);

        // ---- S4/S6: PV via MFMA, 2 j-halves of 16 steps each ----
        {
            unsigned* d12s = (unsigned*)arena;                            // 16KB
            unsigned long long* mbs = (unsigned long long*)(arena + 16384); // [32][33] 8448B
            float* srcs = (float*)(arena + 24832);                        // [4][32]
            f32x4* accsh = (f32x4*)arena;                                 // 32KB after loop
            float* lsh = (float*)(arena + 32768);                         // 512B
            unsigned* mlut = (unsigned*)(arena + 33280);
            float* dmx = (float*)(arena + 33296);
            const unsigned* dml = dmaxu + layer * 1024;
            int it = b & 127, js = b >> 7;
            int hh = wv_ & 3, kq = wv_ >> 2;
            int quad = lane >> 4, c16 = lane & 15;
            int i0 = it * 32;
            int jb0 = js * 2048;
            if (t < 4) mlut[t] = (t & 1 ? 0x0000FFFFu : 0u) | (t & 2 ? 0xFFFF0000u : 0u);
            if (t < 256) {
                int h2 = t >> 6, sl = t & 63;
                float v = fdec(dml[sl * 16 + h2]);
                for (int o = 32; o > 0; o >>= 1) v = fmaxf(v, __shfl_xor(v, o));
                if (sl == 0) dmx[h2] = v;
            }
            for (int idx = t; idx < 32 * 32; idx += NTHR) {
                int r = idx >> 5, wd = idx & 31;
                mbs[r * 33 + wd] = maskb[(size_t)(i0 + r) * 64 + (jb0 >> 6) + wd];
            }
            if (t < 128) {
                int h2 = t >> 5, r = t & 31;
                srcs[h2 * 32 + r] = srcb[h2 * 4096 + i0 + r];
            }
            __syncthreads();
            float dm = dmx[hh];
            float E1[2], E2[2];
#pragma unroll
            for (int rt = 0; rt < 2; rt++) {
                float src = srcs[hh * 32 + rt * 16 + c16];
                float sd = src + dm;
                float rce = -fmaxf(sd, 0.2f * sd);
                E1[rt] = exp2f((src + rce) * LOG2E);
                E2[rt] = exp2f((0.2f * src + rce) * LOG2E);
            }
            f32x4 acc[2][4];
            f32x4 accl[2] = {(f32x4){0.f, 0.f, 0.f, 0.f}, (f32x4){0.f, 0.f, 0.f, 0.f}};
#pragma unroll
            for (int rt = 0; rt < 2; rt++)
#pragma unroll
                for (int ct = 0; ct < 4; ct++) acc[rt][ct] = (f32x4){0.f, 0.f, 0.f, 0.f};
            uint4 onesu;
            unsigned os = (c16 == 0) ? 0x3F803F80u : 0u;
            onesu.x = os; onesu.y = os; onesu.z = os; onesu.w = os;
            short8 bfones = __builtin_bit_cast(short8, onesu);
            const uint4* g4 = (const uint4*)whswz;
            for (int half = 0; half < 2; half++) {
                if (half) __syncthreads();
                for (int idx = t; idx < 1024; idx += NTHR) {
                    int h2 = idx >> 8, j4 = idx & 255;
                    ((uint4*)d12s)[idx] = ((const uint4*)(d12g + h2 * 4096 + jb0 + half * 1024))[j4];
                }
                __syncthreads();
                size_t b0 = (size_t)((jb0 + half * 1024) >> 6) * 2048 + hh * 512 +
                            (kq * 4 + quad) * 64 + c16;
                uint4 bn[4];
#pragma unroll
                for (int ct = 0; ct < 4; ct++) bn[ct] = g4[b0 + ct * 16];
                for (int step = 0; step < 16; step++) {
                    uint4 bc[4];
#pragma unroll
                    for (int ct = 0; ct < 4; ct++) bc[ct] = bn[ct];
                    if (step < 15) {
                        size_t bs = b0 + (size_t)(step + 1) * 2048;
#pragma unroll
                        for (int ct = 0; ct < 4; ct++) bn[ct] = g4[bs + ct * 16];
                    }
                    int jl0 = step * 64 + kq * 32 + quad * 8;
                    unsigned mby[2];
#pragma unroll
                    for (int rt = 0; rt < 2; rt++)
                        mby[rt] = (unsigned)(mbs[(rt * 16 + c16) * 33 + half * 16 + step] >>
                                             (kq * 32 + quad * 8)) & 0xFFu;
                    const uint4* dj = (const uint4*)&d12s[hh * 1024 + jl0];
                    uint4 da = dj[0], db = dj[1];
                    unsigned dw[8] = {da.x, da.y, da.z, da.w, db.x, db.y, db.z, db.w};
                    f32x2 D1[4], D2[4];
#pragma unroll
                    for (int q = 0; q < 4; q++) {
                        unsigned a = dw[2 * q], bb = dw[2 * q + 1];
                        D1[q] = (f32x2){__uint_as_float(a << 16), __uint_as_float(bb << 16)};
                        D2[q] = (f32x2){__uint_as_float(a & 0xFFFF0000u), __uint_as_float(bb & 0xFFFF0000u)};
                    }
                    uint4 afu[2];
#pragma unroll
                    for (int rt = 0; rt < 2; rt++) {
                        unsigned pu[4];
#pragma unroll
                        for (int q = 0; q < 4; q++) {
                            f32x2 v1 = D1[q] * E1[rt];
                            f32x2 v2 = D2[q] * E2[rt];
                            f32x2 m = __builtin_elementwise_max(v1, v2);
                            unsigned v = ((__float_as_uint(m.x) + 0x8000u) >> 16) |
                                         ((__float_as_uint(m.y) + 0x8000u) & 0xFFFF0000u);
                            pu[q] = v & mlut[(mby[rt] >> (2 * q)) & 3u];
                        }
                        afu[rt].x = pu[0]; afu[rt].y = pu[1]; afu[rt].z = pu[2]; afu[rt].w = pu[3];
                    }
                    short8 af0 = __builtin_bit_cast(short8, afu[0]);
                    short8 af1 = __builtin_bit_cast(short8, afu[1]);
#pragma unroll
                    for (int ct = 0; ct < 4; ct++) {
                        short8 bf = __builtin_bit_cast(short8, bc[ct]);
                        acc[0][ct] = __builtin_amdgcn_mfma_f32_16x16x32_bf16(af0, bf, acc[0][ct], 0, 0, 0);
                        acc[1][ct] = __builtin_amdgcn_mfma_f32_16x16x32_bf16(af1, bf, acc[1][ct], 0, 0, 0);
                    }
                    accl[0] = __builtin_amdgcn_mfma_f32_16x16x32_bf16(af0, bfones, accl[0], 0, 0, 0);
                    accl[1] = __builtin_amdgcn_mfma_f32_16x16x32_bf16(af1, bfones, accl[1], 0, 0, 0);
                }
            }
            __syncthreads();                       // d12s/mbs dead; reuse as accsh
            if (kq == 1) {
#pragma unroll
                for (int rt = 0; rt < 2; rt++) {
#pragma unroll
                    for (int ct = 0; ct < 4; ct++)
                        accsh[((hh * 2 + rt) * 4 + ct) * 64 + lane] = acc[rt][ct];
                    if (c16 == 0) *(f32x4*)&lsh[((hh * 2 + rt) * 4 + quad) * 4] = accl[rt];
                }
            }
            __syncthreads();
            if (kq == 0) {
                float* out = hnp + (size_t)js * (TOTAL * 256);
#pragma unroll
                for (int rt = 0; rt < 2; rt++) {
#pragma unroll
                    for (int ct = 0; ct < 4; ct++) {
                        f32x4 o = acc[rt][ct] + accsh[((hh * 2 + rt) * 4 + ct) * 64 + lane];
#pragma unroll
                        for (int rr = 0; rr < 4; rr++) {
                            int row = i0 + rt * 16 + quad * 4 + rr;
                            out[(size_t)row * 256 + hh * 64 + ct * 16 + c16] = o[rr];
                        }
                    }
                    if (c16 == 0) {
                        f32x4 lv = accl[rt] + *(const f32x4*)&lsh[((hh * 2 + rt) * 4 + quad) * 4];
#pragma unroll
                        for (int rr = 0; rr < 4; rr++)
                            lpart[(size_t)(js * 4 + hh) * 4096 + i0 + rt * 16 + quad * 4 + rr] = lv[rr];
                    }
                }
            }
        }
        gbar(barr, 4 + layer * 2);
    }

    // ---- S7: layer-1 epilogue + scores + cos, wave per 2 docs ----
    {
        int hh = lane >> 4;
        float4* h4 = (float4*)h;
        const float4* p0 = (const float4*)hnp;
        const float4* p1 = p0 + (size_t)TOTAL * 64;
        int gw = b * 8 + wv_;
        float lq = lpart[(size_t)hh * 4096] + lpart[(size_t)(4 + hh) * 4096];
        float4 a0 = p0[lane], a1 = p1[lane];
        float4 hq = h4[lane];
        float invq = 1.f / lq;
        float4 q4;
        q4.x = 0.5f * fmaxf((a0.x + a1.x) * invq, 0.f) + 0.5f * hq.x;
        q4.y = 0.5f * fmaxf((a0.y + a1.y) * invq, 0.f) + 0.5f * hq.y;
        q4.z = 0.5f * fmaxf((a0.z + a1.z) * invq, 0.f) + 0.5f * hq.z;
        q4.w = 0.5f * fmaxf((a0.w + a1.w) * invq, 0.f) + 0.5f * hq.w;
        if (gw == 0) ((float4*)qrow)[lane] = q4;
        float a = q4.x * q4.x + q4.y * q4.y + q4.z * q4.z + q4.w * q4.w;
        for (int o = 32; o > 0; o >>= 1) a += __shfl_xor(a, o);
        float qn = sqrtf(a) + 1e-8f;
#pragma unroll
        for (int v = 0; v < 2; v++) {
            int n = v * 2048 + gw;
            if (n < NDOCS) {
                int row = 1 + MD + n;
                size_t ro = (size_t)row * 64;
                float ld = lpart[(size_t)hh * 4096 + row] + lpart[(size_t)(4 + hh) * 4096 + row];
                float4 b0 = p0[ro + lane], b1 = p1[ro + lane];
                float4 ho = h4[ro + lane];
                float invd = 1.f / ld;
                float4 s4;
                s4.x = 0.5f * fmaxf((b0.x + b1.x) * invd, 0.f) + 0.5f * ho.x;
                s4.y = 0.5f * fmaxf((b0.y + b1.y) * invd, 0.f) + 0.5f * ho.y;
                s4.z = 0.5f * fmaxf((b0.z + b1.z) * invd, 0.f) + 0.5f * ho.z;
                s4.w = 0.5f * fmaxf((b0.w + b1.w) * invd, 0.f) + 0.5f * ho.w;
                h4[ro + lane] = s4;
                float bb = s4.x * s4.x + s4.y * s4.y + s4.z * s4.z + s4.w * s4.w;
                float cc = q4.x * s4.x + q4.y * s4.y + q4.z * s4.z + q4.w * s4.w;
                for (int o = 32; o > 0; o >>= 1) { bb += __shfl_xor(bb, o); cc += __shfl_xor(cc, o); }
                if (lane == 0) {
                    scoresv[n] = cc * (1.f / 16.f);
                    cosv[n] = cc / (qn * (sqrtf(bb) + 1e-8f));
                }
            }
        }
    }
    gbar(barr, 7);

    // ---- S8: softmax over scores (block 0 only) ----
    if (b == 0) {
        float* red = (float*)arena;
        float m = -__builtin_inff();
        for (int n = t; n < NDOCS; n += NTHR) m = fmaxf(m, scoresv[n]);
        for (int o = 32; o > 0; o >>= 1) m = fmaxf(m, __shfl_down(m, o));
        if (lane == 0) red[wv_] = m;
        __syncthreads();
        m = red[0];
#pragma unroll
        for (int i = 1; i < 8; i++) m = fmaxf(m, red[i]);
        __syncthreads();
        float s = 0.f;
        for (int n = t; n < NDOCS; n += NTHR) s += __expf(scoresv[n] - m);
        for (int o = 32; o > 0; o >>= 1) s += __shfl_down(s, o);
        if (lane == 0) red[wv_] = s;
        __syncthreads();
        s = 0.f;
#pragma unroll
        for (int i = 0; i < 8; i++) s += red[i];
        float inv = 1.f / s;
        for (int n = t; n < NDOCS; n += NTHR) awv[n] = __expf(scoresv[n] - m) * inv;
    }
    gbar(barr, 8);

    // ---- S9: fused feature GEMM + output, 2 passes of 8 docs/block ----
    for (int v = 0; v < 2; v++) {
        float* feats2 = (float*)arena;             // [514][8]
        float* qhs = (float*)(arena + 16448);      // [256]
        float* redr = (float*)(arena + 17472);     // [8][4]
        float* redc = (float*)(arena + 17600);     // [8][256]
        int col = t & 255, g = t >> 8;
        int n0 = (v * 256 + b) * 8;
        __syncthreads();
        if (t < 256) qhs[t] = qrow[t];
        __syncthreads();
        for (int idx = t; idx < 514 * 8; idx += NTHR) {
            int j = idx >> 3, r = idx & 7;
            int n = n0 + r;
            float vv = 0.f;
            if (n < NDOCS) {
                if (j < 256) vv = h[(size_t)(1 + MD + n) * 256 + j];
                else if (j < 512) vv = qhs[j - 256] * (awv[n] + 0.5f);
                else if (j == 512) vv = cosv[n];
                else vv = awv[n];
            }
            feats2[j * 8 + r] = vv;
        }
        __syncthreads();
        float acc[8];
        float bk = (g == 0) ? ldf(fusion_b, col, isbf) : 0.f;
#pragma unroll
        for (int r = 0; r < 8; r++) acc[r] = bk;
        int jlo = g * 256;
        for (int j0 = jlo; j0 < jlo + 256; j0 += 8) {
            float wv[8];
#pragma unroll
            for (int u = 0; u < 8; u++) wv[u] = fwT[(j0 + u) * 256 + col];
#pragma unroll
            for (int u = 0; u < 8; u++) {
                float4 fa = *(const float4*)&feats2[(j0 + u) * 8];
                float4 fb = *(const float4*)&feats2[(j0 + u) * 8 + 4];
                acc[0] = fmaf(fa.x, wv[u], acc[0]); acc[1] = fmaf(fa.y, wv[u], acc[1]);
                acc[2] = fmaf(fa.z, wv[u], acc[2]); acc[3] = fmaf(fa.w, wv[u], acc[3]);
                acc[4] = fmaf(fb.x, wv[u], acc[4]); acc[5] = fmaf(fb.y, wv[u], acc[5]);
                acc[6] = fmaf(fb.z, wv[u], acc[6]); acc[7] = fmaf(fb.w, wv[u], acc[7]);
            }
        }
        if (g == 1) {
#pragma unroll
            for (int j = 512; j < 514; j++) {
                float wvx = fwT[j * 256 + col];
#pragma unroll
                for (int r = 0; r < 8; r++) acc[r] = fmaf(feats2[j * 8 + r], wvx, acc[r]);
            }
#pragma unroll
            for (int r = 0; r < 8; r++) redc[r * 256 + col] = acc[r];
        }
        __syncthreads();
        float ow = ldf(out_w, col, isbf);
        float outb = ldf(out_bp, 0, isbf);
        if (g == 0) {
#pragma unroll
            for (int r = 0; r < 8; r++) {
                float o = fmaxf(acc[r] + redc[r * 256 + col], 0.f) * ow;
                for (int off = 32; off > 0; off >>= 1) o += __shfl_down(o, off);
                if (lane == 0) redr[r * 4 + wv_] = o;
            }
        }
        __syncthreads();
        if (t < 8) {
            int n = n0 + t;
            if (n < NDOCS) {
                float o = redr[t * 4] + redr[t * 4 + 1] + redr[t * 4 + 2] + redr[t * 4 + 3] +
                          outb + 0.5f * cosv[n];
                if (isbf) ((bf16*)outv)[n] = __float2bfloat16(o);
                else      ((float*)outv)[n] = o;
            }
        }
    }
}

extern "C" void kernel_launch(void* const* d_in, const int* in_sizes, int n_in,
                              void* d_out, int out_size, void* d_ws, size_t ws_size,
                              hipStream_t stream) {
    const void* emb      = d_in[0];
    const int*  adj      = (const int*)d_in[1];
    const void* proj_w   = d_in[3];
    const void* proj_b   = d_in[4];
    const void* ln_scale = d_in[5];
    const void* ln_bias  = d_in[6];
    const void* gat_W    = d_in[7];
    const void* gat_a    = d_in[8];
    const void* fusion_w = d_in[9];
    const void* fusion_b = d_in[10];
    const void* out_w    = d_in[11];
    const void* out_b    = d_in[12];

    unsigned long long* maskb = (unsigned long long*)d_ws;
    unsigned* barr = (unsigned*)((char*)d_ws + (size_t)4096 * 64 * 8);   // 2KB
    float* f = (float*)((char*)d_ws + (size_t)4096 * 64 * 8 + 2048);
    float* h       = f; f += 4096 * 256;
    float* srcb    = f; f += 4 * 4096;
    unsigned* d12g = (unsigned*)f; f += 4 * 4096;
    unsigned* dmaxu = (unsigned*)f; f += 2048;
    float* projT   = f; f += EMB * 256;
    float* gatT    = f; f += 2 * 65536;
    float* fwT     = f; f += 514 * 256;
    float* scoresv = f; f += 4096;
    float* cosv    = f; f += 4096;
    float* awv     = f; f += 4096;
    float* qrow    = f; f += 256;
    float* lpart   = f; f += 2 * 4 * 4096;                 // 2 j-splits x 4 heads
    ushort_t* whswz = (ushort_t*)f; f += 4096 * 256 / 2;   // 2MB
    float* hnp     = f; f += (size_t)2 * 4096 * 256;       // 8MB (2 planes)

    hipMemsetAsync(barr, 0, 2048, stream);
    k_mega<<<dim3(NBLK), dim3(NTHR), 0, stream>>>(
        adj, emb, proj_w, gat_W, fusion_w, proj_b, ln_scale, ln_bias, gat_a,
        fusion_b, out_w, out_b, d_out, barr, maskb, dmaxu, projT, gatT, fwT,
        h, srcb, d12g, whswz, hnp, lpart, scoresv, cosv, awv, qrow);
}

// Round 16
// 302.228 us; speedup vs baseline: 1.6101x; 1.6101x over previous
//
#include <hip/hip_runtime.h>
#include <hip/hip_bf16.h>
#include <stdint.h>

#define TOTAL 4096
#define EMB 384
#define MD 32
#define NDOCS (TOTAL - 1 - MD)   // 4063
#define LN_EPS 1e-5f

typedef __hip_bfloat16 bf16;
typedef unsigned short ushort_t;
typedef __attribute__((ext_vector_type(8))) short short8;
typedef __attribute__((ext_vector_type(4))) float f32x4;
typedef __attribute__((ext_vector_type(2))) float f32x2;

// Dual-dtype load: inputs may be stored bf16 or fp32; isbf selects at runtime.
__device__ __forceinline__ float ldf(const void* p, int i, int isbf) {
    return isbf ? __bfloat162float(((const bf16*)p)[i]) : ((const float*)p)[i];
}

// round-half-up f32 -> bf16 bits
__device__ __forceinline__ unsigned f2bf(float x) {
    return (__float_as_uint(x) + 0x8000u) >> 16;
}

// order-preserving float<->uint for atomicMax over signed floats
__device__ __forceinline__ unsigned fenc(float f) {
    unsigned u = __float_as_uint(f);
    return (u >> 31) ? ~u : (u | 0x80000000u);
}
__device__ __forceinline__ float fdec(unsigned k) {
    return __uint_as_float((k & 0x80000000u) ? (k & 0x7FFFFFFFu) : ~k);
}

// ---------------- adj -> bitmask; + dtype detect + dmax init + weight transpose -------
// Blocks 0..1409 also transpose weights into workspace (coalesced [d*256+c] layout),
// recomputing the dtype flag locally (deterministic — no cross-block race).
#define NTRANS ((EMB * 256 + 2 * 65536 + 514 * 256) / 256)   // 1410
__global__ void k_adjmask(const int* adj, unsigned long long* maskb,
                          const uint16_t* embp, int* flag, unsigned* dmaxu,
                          const void* proj_w, const void* gat_W, const void* fusion_w,
                          float* projT, float* gatT, float* fwT) {
    __shared__ int red[4];
    int i = blockIdx.x, t = threadIdx.x;
    int w = t >> 6, l = t & 63;
    for (int c = w; c < 64; c += 4) {
        int a = adj[(size_t)i * TOTAL + c * 64 + l];
        unsigned long long m = __ballot(a != 0);
        if (l == 0) maskb[i * 64 + c] = m;
    }
    if (i == 0) {                                  // init 2 layers x 64 slots x 16
        for (int idx = t; idx < 2048; idx += 256) dmaxu[idx] = 0x007FFFFFu;  // fenc(-inf)
    }
    if (i < NTRANS) {
        int cnt = 0;
        for (int k = t; k < 4096; k += 256) {
            uint16_t wd = embp[2 * k];
            int e = (wd >> 7) & 0xFF;
            if (e >= 100 && e <= 140) cnt++;
        }
        for (int o = 32; o > 0; o >>= 1) cnt += __shfl_down(cnt, o);
        if ((t & 63) == 0) red[t >> 6] = cnt;
        __syncthreads();
        int isbf = (red[0] + red[1] + red[2] + red[3] > 2048) ? 1 : 0;
        if (i == 0 && t == 0) flag[0] = isbf;
        int idx = i * 256 + t;
        if (idx < EMB * 256) {                      // projT[d*256+c] = proj_w[c*EMB+d]
            int d = idx >> 8, c = idx & 255;
            projT[idx] = ldf(proj_w, c * EMB + d, isbf);
        } else if (idx < EMB * 256 + 2 * 65536) {
            int r = idx - EMB * 256;
            int ll = r >> 16, rem = r & 65535;
            int d = rem >> 8, c = rem & 255;        // gatT[l][d*256+c] = gat_W[l][c*256+d]
            gatT[r] = ldf(gat_W, ll * 65536 + c * 256 + d, isbf);
        } else {
            int r = idx - (EMB * 256 + 2 * 65536);
            int j = r >> 8, c = r & 255;            // fwT[j*256+c] = fusion_w[c*514+j]
            fwT[r] = ldf(fusion_w, c * 514 + j, isbf);
        }
    }
}

// ---------------- h = relu(emb @ projT + b), coalesced transposed weights -------------
#define PR 8
__global__ void k_proj(const void* emb, const void* proj_b, const float* projT, float* h,
                       const int* flagp) {
    __shared__ float xs[PR][EMB];
    int isbf = flagp[0];
    int i0 = blockIdx.x * PR, t = threadIdx.x;
    for (int idx = t; idx < PR * EMB; idx += 256) {
        int r = idx / EMB, d = idx % EMB;
        xs[r][d] = ldf(emb, (i0 + r) * EMB + d, isbf);
    }
    __syncthreads();
    float acc[PR];
    float bias = ldf(proj_b, t, isbf);
#pragma unroll
    for (int r = 0; r < PR; r++) acc[r] = bias;
    for (int d0 = 0; d0 < EMB; d0 += 4) {
        float w0 = projT[d0 * 256 + t];
        float w1 = projT[(d0 + 1) * 256 + t];
        float w2 = projT[(d0 + 2) * 256 + t];
        float w3 = projT[(d0 + 3) * 256 + t];
#pragma unroll
        for (int r = 0; r < PR; r++) {
            float4 x = *(const float4*)&xs[r][d0];
            acc[r] = fmaf(x.x, w0, acc[r]);
            acc[r] = fmaf(x.y, w1, acc[r]);
            acc[r] = fmaf(x.z, w2, acc[r]);
            acc[r] = fmaf(x.w, w3, acc[r]);
        }
    }
#pragma unroll
    for (int r = 0; r < PR; r++) h[(size_t)(i0 + r) * 256 + t] = fmaxf(acc[r], 0.f);
}

// ---------------- query-aware doc update: s += 0.8*cos(q,s)*q (wave-per-row) ----------
__global__ __launch_bounds__(256) void k_cosupdate(float* h) {
    int t = threadIdx.x, W = t >> 6, lane = t & 63;
    float4* h4 = (float4*)h;
    float4 q4 = h4[lane];
    float a = q4.x * q4.x + q4.y * q4.y + q4.z * q4.z + q4.w * q4.w;
    for (int o = 32; o > 0; o >>= 1) a += __shfl_xor(a, o);
    float qn = sqrtf(a) + 1e-8f;
    int gw = blockIdx.x * 4 + W;
    for (int n = gw; n < NDOCS; n += 1024) {
        size_t ro = (size_t)(1 + MD + n) * 64;
        float4 s4 = h4[ro + lane];
        float b = s4.x * s4.x + s4.y * s4.y + s4.z * s4.z + s4.w * s4.w;
        float c = q4.x * s4.x + q4.y * s4.y + q4.z * s4.z + q4.w * s4.w;
        for (int o = 32; o > 0; o >>= 1) { b += __shfl_xor(b, o); c += __shfl_xor(c, o); }
        float k = 0.8f * (c / (qn * (sqrtf(b) + 1e-8f)));
        s4.x += k * q4.x; s4.y += k * q4.y; s4.z += k * q4.z; s4.w += k * q4.w;
        h4[ro + lane] = s4;
    }
}

// ---------------- [prev-layer epilogue] + layernorm + Wh GEMM + src/dst ---------------
// whswz: B-frag order (16B contiguous per k_pv lane). d12g[h][j]=pack_bf16(D2,D1),
// D1=exp(dst), D2=exp(0.2*dst). dmax via SPREAD atomicMax: slot (blockIdx&63)*16+head,
// one slot group per cache line — avoids same-line atomic serialization (R9 lesson).
#define LR 4
__global__ void k_ln_wh(float* h, const float* gatT, const void* ln_scale,
                        const void* ln_bias, const void* gat_a,
                        ushort_t* whswz, float* srcb, unsigned* d12g, unsigned* dmaxu,
                        const float* hnp, const float* lpart, int layer, int doepi,
                        const int* flagp) {
    __shared__ float xs[LR][256];
    __shared__ float red[2][LR][4];
    int isbf = flagp[0];
    int i0 = blockIdx.x * LR, t = threadIdx.x;
    int w = t >> 6, l = t & 63;
    float scale = ldf(ln_scale, layer * 256 + t, isbf);
    float bias = ldf(ln_bias, layer * 256 + t, isbf);
    float hv[LR];
    if (doepi) {
#pragma unroll
        for (int r = 0; r < LR; r++) {
            int i = i0 + r;
            float lsum = lpart[(size_t)w * 4096 + i] + lpart[(size_t)(4 + w) * 4096 + i] +
                         lpart[(size_t)(8 + w) * 4096 + i] + lpart[(size_t)(12 + w) * 4096 + i];
            float s = hnp[(size_t)i * 256 + t] + hnp[(size_t)TOTAL * 256 + i * 256 + t] +
                      hnp[(size_t)2 * TOTAL * 256 + i * 256 + t] +
                      hnp[(size_t)3 * TOTAL * 256 + i * 256 + t];
            float hn = 0.5f * fmaxf(s / lsum, 0.f) + 0.5f * h[(size_t)i * 256 + t];
            hv[r] = hn;
            h[(size_t)i * 256 + t] = hn;
        }
    } else {
#pragma unroll
        for (int r = 0; r < LR; r++) hv[r] = h[(size_t)(i0 + r) * 256 + t];
    }
#pragma unroll
    for (int r = 0; r < LR; r++) {
        float a = hv[r], b = hv[r] * hv[r];
        for (int o = 32; o > 0; o >>= 1) { a += __shfl_down(a, o); b += __shfl_down(b, o); }
        if (l == 0) { red[0][r][w] = a; red[1][r][w] = b; }
    }
    __syncthreads();
#pragma unroll
    for (int r = 0; r < LR; r++) {
        float mu = (red[0][r][0] + red[0][r][1] + red[0][r][2] + red[0][r][3]) * (1.f / 256.f);
        float var = (red[1][r][0] + red[1][r][1] + red[1][r][2] + red[1][r][3]) * (1.f / 256.f) - mu * mu;
        float x = (hv[r] - mu) * rsqrtf(var + LN_EPS) * scale + bias;
        xs[r][t] = x;
    }
    __syncthreads();
    const float* gT = gatT + layer * 65536;
    float acc[LR] = {0.f, 0.f, 0.f, 0.f};
    for (int d0 = 0; d0 < 256; d0 += 4) {
        float w0 = gT[d0 * 256 + t];
        float w1 = gT[(d0 + 1) * 256 + t];
        float w2 = gT[(d0 + 2) * 256 + t];
        float w3 = gT[(d0 + 3) * 256 + t];
#pragma unroll
        for (int r = 0; r < LR; r++) {
            float4 x = *(const float4*)&xs[r][d0];
            acc[r] = fmaf(x.x, w0, acc[r]);
            acc[r] = fmaf(x.y, w1, acc[r]);
            acc[r] = fmaf(x.z, w2, acc[r]);
            acc[r] = fmaf(x.w, w3, acc[r]);
        }
    }
    float av1 = ldf(gat_a, layer * 512 + w * 128 + l, isbf);
    float av2 = ldf(gat_a, layer * 512 + w * 128 + 64 + l, isbf);
    const float LOG2E = 1.44269504f;
    float mmax = -__builtin_inff();
#pragma unroll
    for (int r = 0; r < LR; r++) {
        int i = i0 + r;
        int off = (i >> 6) * 16384 + (t >> 6) * 4096 + ((i >> 3) & 7) * 512 +
                  ((t >> 4) & 3) * 128 + (t & 15) * 8 + (i & 7);
        whswz[off] = (ushort_t)f2bf(acc[r]);
        float sv = acc[r] * av1, dv = acc[r] * av2;
        for (int o = 32; o > 0; o >>= 1) { sv += __shfl_down(sv, o); dv += __shfl_down(dv, o); }
        if (l == 0) {
            srcb[w * 4096 + i] = sv;
            float D1 = exp2f(dv * LOG2E), D2 = exp2f(0.2f * dv * LOG2E);
            d12g[w * 4096 + i] = (f2bf(D2) << 16) | f2bf(D1);
            mmax = fmaxf(mmax, dv);
        }
    }
    if (l == 0) atomicMax(&dmaxu[(blockIdx.x & 63) * 16 + w], fenc(mmax));
}

// ---------------- PV via MFMA, barrier-free, exp-free inner loop ----------------------
// p = max(E1_i*D1_j, E2_i*D2_j)  (order of 2^x preserved; mhat shift keeps p<=1).
// Row-sum l via 5th MFMA vs ones-column. Grid (128 x JS), 8 waves = 4 heads x 2 kq.
#define TI 32
#define JS 4
__global__ __launch_bounds__(512) void k_pv(const ushort_t* whswz, const float* srcb,
                                            const unsigned* dmaxu, const unsigned* d12g,
                                            const unsigned long long* maskb,
                                            float* hnp, float* lpart) {
    __shared__ __align__(16) char smem[32768];     // union: {d12s,mbs,srcs} / accsh
    __shared__ __align__(16) float lsh[4][2][4][4];
    __shared__ unsigned mlut[4];
    __shared__ float dmx[4];
    unsigned* d12s = (unsigned*)smem;              // [4][1024] 16KB
    unsigned long long* mbs = (unsigned long long*)(smem + 16384);  // [TI][17]
    float* srcs = (float*)(smem + 16384 + 4352);   // [4][32]
    f32x4* accsh = (f32x4*)smem;                   // 32KB, after K-loop
    int t = threadIdx.x;
    int W = t >> 6, lane = t & 63;
    int h = W & 3, kq = W >> 2;
    int quad = lane >> 4, c16 = lane & 15;
    int i0 = blockIdx.x * TI;
    int jbase = blockIdx.y * 1024;
    if (t < 4) mlut[t] = (t & 1 ? 0x0000FFFFu : 0u) | (t & 2 ? 0xFFFF0000u : 0u);
    if (t < 256) {                                 // wave w reduces head w's 64 dmax slots
        int hh = t >> 6, sl = t & 63;
        float v = fdec(dmaxu[sl * 16 + hh]);
        for (int o = 32; o > 0; o >>= 1) v = fmaxf(v, __shfl_xor(v, o));
        if (sl == 0) dmx[hh] = v;
    }
    for (int idx = t; idx < TI * 16; idx += 512) {
        int r = idx >> 4, wd = idx & 15;
        mbs[r * 17 + wd] = maskb[(size_t)(i0 + r) * 64 + (jbase >> 6) + wd];
    }
    for (int idx = t; idx < 1024; idx += 512) {
        int hh = idx >> 8, j4 = idx & 255;
        ((uint4*)d12s)[idx] = ((const uint4*)(d12g + hh * 4096 + jbase))[j4];
    }
    if (t < 128) {
        int h2 = t >> 5, r = t & 31;
        srcs[h2 * 32 + r] = srcb[h2 * 4096 + i0 + r];
    }
    __syncthreads();
    const float LOG2E = 1.44269504f;
    float dm = dmx[h];
    float E1[2], E2[2];
#pragma unroll
    for (int rt = 0; rt < 2; rt++) {
        float src = srcs[h * 32 + rt * 16 + c16];
        float sd = src + dm;
        float rce = -fmaxf(sd, 0.2f * sd);         // -mhat >= true masked max
        E1[rt] = exp2f((src + rce) * LOG2E);
        E2[rt] = exp2f((0.2f * src + rce) * LOG2E);
    }
    f32x4 acc[2][4];
    f32x4 accl[2] = {(f32x4){0.f, 0.f, 0.f, 0.f}, (f32x4){0.f, 0.f, 0.f, 0.f}};
#pragma unroll
    for (int rt = 0; rt < 2; rt++)
#pragma unroll
        for (int ct = 0; ct < 4; ct++) acc[rt][ct] = (f32x4){0.f, 0.f, 0.f, 0.f};
    uint4 onesu;                                   // B ones-column frag (col c16==0)
    unsigned os = (c16 == 0) ? 0x3F803F80u : 0u;
    onesu.x = os; onesu.y = os; onesu.z = os; onesu.w = os;
    short8 bfones = __builtin_bit_cast(short8, onesu);
    const uint4* g4 = (const uint4*)whswz;
    size_t b0 = (size_t)(jbase >> 6) * 2048 + h * 512 + (kq * 4 + quad) * 64 + c16;
    uint4 bn[4];
#pragma unroll
    for (int ct = 0; ct < 4; ct++) bn[ct] = g4[b0 + ct * 16];
    for (int step = 0; step < 16; step++) {
        uint4 bc[4];
#pragma unroll
        for (int ct = 0; ct < 4; ct++) bc[ct] = bn[ct];
        if (step < 15) {
            size_t bs = b0 + (size_t)(step + 1) * 2048;
#pragma unroll
            for (int ct = 0; ct < 4; ct++) bn[ct] = g4[bs + ct * 16];
        }
        int jl0 = step * 64 + kq * 32 + quad * 8;
        unsigned mby[2];
#pragma unroll
        for (int rt = 0; rt < 2; rt++)
            mby[rt] = (unsigned)(mbs[(rt * 16 + c16) * 17 + step] >> (kq * 32 + quad * 8)) & 0xFFu;
        const uint4* dj = (const uint4*)&d12s[h * 1024 + jl0];
        uint4 da = dj[0], db = dj[1];
        unsigned dw[8] = {da.x, da.y, da.z, da.w, db.x, db.y, db.z, db.w};
        f32x2 D1[4], D2[4];
#pragma unroll
        for (int q = 0; q < 4; q++) {
            unsigned a = dw[2 * q], b = dw[2 * q + 1];
            D1[q] = (f32x2){__uint_as_float(a << 16), __uint_as_float(b << 16)};
            D2[q] = (f32x2){__uint_as_float(a & 0xFFFF0000u), __uint_as_float(b & 0xFFFF0000u)};
        }
        uint4 afu[2];
#pragma unroll
        for (int rt = 0; rt < 2; rt++) {
            unsigned pu[4];
#pragma unroll
            for (int q = 0; q < 4; q++) {
                f32x2 v1 = D1[q] * E1[rt];
                f32x2 v2 = D2[q] * E2[rt];
                f32x2 m = __builtin_elementwise_max(v1, v2);
                unsigned v = ((__float_as_uint(m.x) + 0x8000u) >> 16) |
                             ((__float_as_uint(m.y) + 0x8000u) & 0xFFFF0000u);
                pu[q] = v & mlut[(mby[rt] >> (2 * q)) & 3u];
            }
            afu[rt].x = pu[0]; afu[rt].y = pu[1]; afu[rt].z = pu[2]; afu[rt].w = pu[3];
        }
        short8 af0 = __builtin_bit_cast(short8, afu[0]);
        short8 af1 = __builtin_bit_cast(short8, afu[1]);
#pragma unroll
        for (int ct = 0; ct < 4; ct++) {
            short8 bf = __builtin_bit_cast(short8, bc[ct]);
            acc[0][ct] = __builtin_amdgcn_mfma_f32_16x16x32_bf16(af0, bf, acc[0][ct], 0, 0, 0);
            acc[1][ct] = __builtin_amdgcn_mfma_f32_16x16x32_bf16(af1, bf, acc[1][ct], 0, 0, 0);
        }
        accl[0] = __builtin_amdgcn_mfma_f32_16x16x32_bf16(af0, bfones, accl[0], 0, 0, 0);
        accl[1] = __builtin_amdgcn_mfma_f32_16x16x32_bf16(af1, bfones, accl[1], 0, 0, 0);
    }
    __syncthreads();                               // region A dead; reuse as accsh
    if (kq == 1) {
#pragma unroll
        for (int rt = 0; rt < 2; rt++) {
#pragma unroll
            for (int ct = 0; ct < 4; ct++)
                accsh[((h * 2 + rt) * 4 + ct) * 64 + lane] = acc[rt][ct];
            if (c16 == 0) *(f32x4*)&lsh[h][rt][quad][0] = accl[rt];
        }
    }
    __syncthreads();
    if (kq == 0) {
        float* out = hnp + (size_t)blockIdx.y * (TOTAL * 256);
#pragma unroll
        for (int rt = 0; rt < 2; rt++) {
#pragma unroll
            for (int ct = 0; ct < 4; ct++) {
                f32x4 o = acc[rt][ct] + accsh[((h * 2 + rt) * 4 + ct) * 64 + lane];
#pragma unroll
                for (int rr = 0; rr < 4; rr++) {   // D: col=lane&15, row=quad*4+rr
                    int row = i0 + rt * 16 + quad * 4 + rr;
                    out[(size_t)row * 256 + h * 64 + ct * 16 + c16] = o[rr];
                }
            }
            if (c16 == 0) {
                f32x4 lv = accl[rt] + *(const f32x4*)&lsh[h][rt][quad][0];
#pragma unroll
                for (int rr = 0; rr < 4; rr++)
                    lpart[(size_t)(blockIdx.y * 4 + h) * 4096 + i0 + rt * 16 + quad * 4 + rr] = lv[rr];
            }
        }
    }
}

// ---------------- scores + cos, fused with layer-1 epilogue (wave-per-row) ------------
__global__ __launch_bounds__(256) void k_scores(float* h, const float* hnp, const float* lpart,
                                                float* qrow, float* scoresv, float* cosv) {
    int t = threadIdx.x, W = t >> 6, lane = t & 63;
    int hh = lane >> 4;
    float4* h4 = (float4*)h;
    const float4* p0 = (const float4*)hnp;
    const float4* p1 = p0 + (size_t)TOTAL * 64;
    const float4* p2 = p1 + (size_t)TOTAL * 64;
    const float4* p3 = p2 + (size_t)TOTAL * 64;
    int gw = blockIdx.x * 4 + W;
    // q-row epilogue (all waves compute; only gw==0 writes qrow; h[0..255] untouched)
    float lq = lpart[(size_t)hh * 4096] + lpart[(size_t)(4 + hh) * 4096] +
               lpart[(size_t)(8 + hh) * 4096] + lpart[(size_t)(12 + hh) * 4096];
    float4 a0 = p0[lane], a1 = p1[lane], a2 = p2[lane], a3 = p3[lane];
    float4 hq = h4[lane];
    float invq = 1.f / lq;
    float4 q4;
    q4.x = 0.5f * fmaxf((a0.x + a1.x + a2.x + a3.x) * invq, 0.f) + 0.5f * hq.x;
    q4.y = 0.5f * fmaxf((a0.y + a1.y + a2.y + a3.y) * invq, 0.f) + 0.5f * hq.y;
    q4.z = 0.5f * fmaxf((a0.z + a1.z + a2.z + a3.z) * invq, 0.f) + 0.5f * hq.z;
    q4.w = 0.5f * fmaxf((a0.w + a1.w + a2.w + a3.w) * invq, 0.f) + 0.5f * hq.w;
    if (gw == 0) ((float4*)qrow)[lane] = q4;
    float a = q4.x * q4.x + q4.y * q4.y + q4.z * q4.z + q4.w * q4.w;
    for (int o = 32; o > 0; o >>= 1) a += __shfl_xor(a, o);
    float qn = sqrtf(a) + 1e-8f;
    for (int n = gw; n < NDOCS; n += 1024) {
        int row = 1 + MD + n;
        size_t ro = (size_t)row * 64;
        float ld = lpart[(size_t)hh * 4096 + row] + lpart[(size_t)(4 + hh) * 4096 + row] +
                   lpart[(size_t)(8 + hh) * 4096 + row] + lpart[(size_t)(12 + hh) * 4096 + row];
        float4 b0 = p0[ro + lane], b1 = p1[ro + lane], b2 = p2[ro + lane], b3 = p3[ro + lane];
        float4 ho = h4[ro + lane];
        float invd = 1.f / ld;
        float4 s4;
        s4.x = 0.5f * fmaxf((b0.x + b1.x + b2.x + b3.x) * invd, 0.f) + 0.5f * ho.x;
        s4.y = 0.5f * fmaxf((b0.y + b1.y + b2.y + b3.y) * invd, 0.f) + 0.5f * ho.y;
        s4.z = 0.5f * fmaxf((b0.z + b1.z + b2.z + b3.z) * invd, 0.f) + 0.5f * ho.z;
        s4.w = 0.5f * fmaxf((b0.w + b1.w + b2.w + b3.w) * invd, 0.f) + 0.5f * ho.w;
        h4[ro + lane] = s4;
        float b = s4.x * s4.x + s4.y * s4.y + s4.z * s4.z + s4.w * s4.w;
        float c = q4.x * s4.x + q4.y * s4.y + q4.z * s4.z + q4.w * s4.w;
        for (int o = 32; o > 0; o >>= 1) { b += __shfl_xor(b, o); c += __shfl_xor(c, o); }
        if (lane == 0) {
            scoresv[n] = c * (1.f / 16.f);
            cosv[n] = c / (qn * (sqrtf(b) + 1e-8f));
        }
    }
}

// ---------------- softmax over scores (single block, 1024 thr) ------------------------
__global__ __launch_bounds__(1024) void k_softmax(const float* scoresv, float* awv) {
    __shared__ float red[16];
    int t = threadIdx.x;
    float m = -__builtin_inff();
    for (int n = t; n < NDOCS; n += 1024) m = fmaxf(m, scoresv[n]);
    for (int o = 32; o > 0; o >>= 1) m = fmaxf(m, __shfl_down(m, o));
    if ((t & 63) == 0) red[t >> 6] = m;
    __syncthreads();
    m = red[0];
#pragma unroll
    for (int i = 1; i < 16; i++) m = fmaxf(m, red[i]);
    __syncthreads();
    float s = 0.f;
    for (int n = t; n < NDOCS; n += 1024) s += __expf(scoresv[n] - m);
    for (int o = 32; o > 0; o >>= 1) s += __shfl_down(s, o);
    if ((t & 63) == 0) red[t >> 6] = s;
    __syncthreads();
    s = 0.f;
#pragma unroll
    for (int i = 0; i < 16; i++) s += red[i];
    float inv = 1.f / s;
    for (int n = t; n < NDOCS; n += 1024) awv[n] = __expf(scoresv[n] - m) * inv;
}

// ---------------- fused feature GEMM + output (coalesced fwT reads) -------------------
#define TN 8
__global__ __launch_bounds__(256) void k_fusion(const float* h, const float* qrow,
                                                const float* awv, const float* cosv,
                                                const float* fwT, const void* fusion_b,
                                                const void* out_w, const void* out_bp,
                                                void* outv, const int* flagp) {
    __shared__ float feats2[514][TN];
    __shared__ float qhs[256];
    __shared__ float red[TN][4];
    int isbf = flagp[0];
    int t = threadIdx.x;
    int n0 = blockIdx.x * TN;
    qhs[t] = qrow[t];
    __syncthreads();
    for (int idx = t; idx < 514 * TN; idx += 256) {
        int j = idx >> 3, r = idx & 7;
        int n = n0 + r;
        float v = 0.f;
        if (n < NDOCS) {
            if (j < 256) v = h[(size_t)(1 + MD + n) * 256 + j];
            else if (j < 512) v = qhs[j - 256] * (awv[n] + 0.5f);
            else if (j == 512) v = cosv[n];
            else v = awv[n];
        }
        feats2[j][r] = v;
    }
    __syncthreads();
    float acc[TN];
    float bk = ldf(fusion_b, t, isbf);
#pragma unroll
    for (int r = 0; r < TN; r++) acc[r] = bk;
    for (int j0 = 0; j0 < 512; j0 += 8) {        // 8 independent weight loads in flight
        float wv[8];
#pragma unroll
        for (int u = 0; u < 8; u++) wv[u] = fwT[(j0 + u) * 256 + t];
#pragma unroll
        for (int u = 0; u < 8; u++) {
            float4 fa = *(const float4*)&feats2[j0 + u][0];
            float4 fb = *(const float4*)&feats2[j0 + u][4];
            acc[0] = fmaf(fa.x, wv[u], acc[0]); acc[1] = fmaf(fa.y, wv[u], acc[1]);
            acc[2] = fmaf(fa.z, wv[u], acc[2]); acc[3] = fmaf(fa.w, wv[u], acc[3]);
            acc[4] = fmaf(fb.x, wv[u], acc[4]); acc[5] = fmaf(fb.y, wv[u], acc[5]);
            acc[6] = fmaf(fb.z, wv[u], acc[6]); acc[7] = fmaf(fb.w, wv[u], acc[7]);
        }
    }
#pragma unroll
    for (int j = 512; j < 514; j++) {
        float wv = fwT[j * 256 + t];
#pragma unroll
        for (int r = 0; r < TN; r++) acc[r] = fmaf(feats2[j][r], wv, acc[r]);
    }
    float ow = ldf(out_w, t, isbf);
    float outb = ldf(out_bp, 0, isbf);
#pragma unroll
    for (int r = 0; r < TN; r++) {
        float o = fmaxf(acc[r], 0.f) * ow;
        for (int off = 32; off > 0; off >>= 1) o += __shfl_down(o, off);
        if ((t & 63) == 0) red[r][t >> 6] = o;
    }
    __syncthreads();
    if (t < TN) {
        int n = n0 + t;
        if (n < NDOCS) {
            float o = red[t][0] + red[t][1] + red[t][2] + red[t][3] + outb + 0.5f * cosv[n];
            if (isbf) ((bf16*)outv)[n] = __float2bfloat16(o);
            else      ((float*)outv)[n] = o;
        }
    }
}

extern "C" void kernel_launch(void* const* d_in, const int* in_sizes, int n_in,
                              void* d_out, int out_size, void* d_ws, size_t ws_size,
                              hipStream_t stream) {
    const void* emb      = d_in[0];
    const int*  adj      = (const int*)d_in[1];
    const void* proj_w   = d_in[3];
    const void* proj_b   = d_in[4];
    const void* ln_scale = d_in[5];
    const void* ln_bias  = d_in[6];
    const void* gat_W    = d_in[7];
    const void* gat_a    = d_in[8];
    const void* fusion_w = d_in[9];
    const void* fusion_b = d_in[10];
    const void* out_w    = d_in[11];
    const void* out_b    = d_in[12];

    unsigned long long* maskb = (unsigned long long*)d_ws;
    int* flag = (int*)((char*)d_ws + (size_t)4096 * 64 * 8);
    float* f = (float*)((char*)d_ws + (size_t)4096 * 64 * 8 + 256);
    float* h       = f; f += 4096 * 256;
    float* srcb    = f; f += 4 * 4096;
    unsigned* d12g = (unsigned*)f; f += 4 * 4096;
    unsigned* dmaxu = (unsigned*)f; f += 2048;             // 2 layers x 64 slots x 16
    float* projT   = f; f += EMB * 256;
    float* gatT    = f; f += 2 * 65536;
    float* fwT     = f; f += 514 * 256;
    float* scoresv = f; f += 4096;
    float* cosv    = f; f += 4096;
    float* awv     = f; f += 4096;
    float* qrow    = f; f += 256;
    float* lpart   = f; f += 4 * 4 * 4096;                 // 256KB
    ushort_t* whswz = (ushort_t*)f; f += 4096 * 256 / 2;   // 2MB
    float* hnp     = f; f += (size_t)JS * 4096 * 256;      // 16MB partials

    k_adjmask<<<dim3(4096), dim3(256), 0, stream>>>(adj, maskb, (const uint16_t*)emb, flag,
                                                    dmaxu, proj_w, gat_W, fusion_w,
                                                    projT, gatT, fwT);
    k_proj<<<dim3(TOTAL / PR), dim3(256), 0, stream>>>(emb, proj_b, projT, h, flag);
    k_cosupdate<<<dim3(256), dim3(256), 0, stream>>>(h);
    for (int layer = 0; layer < 2; layer++) {
        k_ln_wh<<<dim3(TOTAL / LR), dim3(256), 0, stream>>>(h, gatT, ln_scale, ln_bias, gat_a,
                                                            whswz, srcb, d12g, dmaxu + layer * 1024,
                                                            hnp, lpart, layer, layer, flag);
        k_pv<<<dim3(TOTAL / TI, JS), dim3(512), 0, stream>>>(whswz, srcb, dmaxu + layer * 1024,
                                                             d12g, maskb, hnp, lpart);
    }
    k_scores<<<dim3(256), dim3(256), 0, stream>>>(h, hnp, lpart, qrow, scoresv, cosv);
    k_softmax<<<dim3(1), dim3(1024), 0, stream>>>(scoresv, awv);
    k_fusion<<<dim3((NDOCS + TN - 1) / TN), dim3(256), 0, stream>>>(h, qrow, awv, cosv,
                                                                    fwT, fusion_b, out_w,
                                                                    out_b, (void*)d_out, flag);
}